// Round 10
// baseline (291.138 us; speedup 1.0000x reference)
//
#include <hip/hip_runtime.h>
#include <stdint.h>

#define D_DIM 256
#define BI 128       // i-rows per block
#define TJ 128       // j-tile
#define CHUNK 4096   // j per block (grid = 64 x 4 = 256 blocks = 1/CU)

typedef unsigned short ushort_t;
typedef __attribute__((ext_vector_type(8))) short bf16x8;   // 8 bf16 = 4 VGPRs
typedef __attribute__((ext_vector_type(4))) float f32x4;

__device__ __forceinline__ unsigned short f2bf(float f) {
  union { float f; unsigned u; } x; x.f = f;
  unsigned r = x.u + 0x7FFFu + ((x.u >> 16) & 1u);  // round-nearest-even
  return (unsigned short)(r >> 16);
}

__device__ __forceinline__ float fast_sqrt(float x) {
#if __has_builtin(__builtin_amdgcn_sqrtf)
  return __builtin_amdgcn_sqrtf(x);
#else
  return sqrtf(x);
#endif
}
__device__ __forceinline__ float fast_exp2(float x) {
#if __has_builtin(__builtin_amdgcn_exp2f)
  return __builtin_amdgcn_exp2f(x);
#else
  return exp2f(x);
#endif
}

// async global->LDS, 16B per lane. LDS dest = wave-uniform base + lane*16.
__device__ __forceinline__ void g2l16(const void* g, void* l) {
  __builtin_amdgcn_global_load_lds(
      (__attribute__((address_space(1))) void*)(uintptr_t)g,
      (__attribute__((address_space(3))) void*)(unsigned)(uintptr_t)l,
      16, 0, 0);
}

// ---------------- prep: cast + norms + TbF + TTF, all fused ----------------
// block = 32 rows (r0 = b*32), 256 threads.
__global__ __launch_bounds__(256) void
prep_ABT(const float* __restrict__ G, const float* __restrict__ P,
         ushort_t* __restrict__ Tb, ushort_t* __restrict__ TbF,
         ushort_t* __restrict__ TTF, float* __restrict__ nrm, int Bn, int Ttot)
{
  __shared__ ushort_t Ls[32 * 264];   // padded stride (528 B = 33*16, 16B-aligned rows)
  const int b = blockIdx.x, t = threadIdx.x, lane = t & 63;
  const int r0 = b * 32;
  const int jsteps = Ttot >> 5;

  #pragma unroll
  for (int it = 0; it < 32; it++) {
    const int r = r0 + it;
    const float* src = (r < Bn) ? (G + (size_t)r * D_DIM)
                                : (P + (size_t)(r - Bn) * D_DIM);
    float v = src[t];
    ushort_t u = f2bf(v);
    Tb[(size_t)r * D_DIM + t] = u;
    Ls[it * 264 + t] = u;
    float s = v * v;
    #pragma unroll
    for (int o = 32; o > 0; o >>= 1) s += __shfl_down(s, o, 64);
    if (lane == 0) atomicAdd(&nrm[r], s);
  }
  __syncthreads();

  // TbF: fragment-linear A layout. 1024 16B-chunks, 4 per thread.
  #pragma unroll
  for (int itc = 0; itc < 4; itc++) {
    int ch = itc * 256 + t;                       // [0,1024)
    int jl = ch >> 9;                             // local jgrp (0/1)
    int ch2 = ch & 511;
    int ks = ch2 >> 6, rem = ch2 & 63, qq = rem >> 4, m = rem & 15;
    uint4 val = *(const uint4*)&Ls[(jl * 16 + m) * 264 + ks * 32 + qq * 8];
    *(uint4*)&TbF[((size_t)(b * 2 + jl) * 8 + ks) * 512 + qq * 128 + m * 8] = val;
  }

  // TTF: transposed fragment-linear. jstep = b. 1024 16B-chunks, 4 per thread.
  #pragma unroll
  for (int itc = 0; itc < 4; itc++) {
    int ch = itc * 256 + t;                       // [0,1024)
    int dgrp = ch >> 6, rem = ch & 63, qq = rem >> 4, m = rem & 15;
    ushort_t tmp[8];
    #pragma unroll
    for (int idx = 0; idx < 8; idx++)
      tmp[idx] = Ls[(qq * 8 + idx) * 264 + dgrp * 16 + m];
    *(uint4*)&TTF[((size_t)dgrp * jsteps + b) * 512 + qq * 128 + m * 8] = *(uint4*)tmp;
  }
}

// ---------------- fused: S^T -> kv (LDS dbuf) -> O^T, 1 barrier/tile ----------------
// 512 thr / 8 fat waves / 1 block per CU (256-reg cap via launch_bounds(512,2)).
// GEMM1 (S^T 128j x 128i): wave (wj=w>>1, wcol=w&1) owns 32j x 64i; acc1[2][4]=32 regs.
//   A-frags = TbF global stream (reg-dbuf 1 ahead); B-frags from resident swizzled Gsm.
// Epilogue: kv = exp(-dist/20) -> Ksm[parity]; rowsums in regs. ONE barrier.
// GEMM2 (O^T 256d x 128i): wave (wd=w>>1, wi=w&1) owns 64d x 64i; accO[4][4]=64 regs.
//   A-frags = TTF global stream (reg-dbuf); B-frags = Ksm (reg-dbuf).
__global__ __launch_bounds__(512, 2) void
fused_kernel(const ushort_t* __restrict__ Tb, const ushort_t* __restrict__ TbF,
             const ushort_t* __restrict__ TTF, const float* __restrict__ nrm,
             float* __restrict__ sg, float* __restrict__ sp,
             float* __restrict__ Part, int Bn, int Ttot)
{
  __shared__ ushort_t Gsm[4 * 8192];      // 64 KB resident i-tile: [kq][row][64 ^ swz]
  __shared__ ushort_t Ksm[2][128 * 128];  // 2 x 32 KB kv: [i][128j ^ swz]

  const int t = threadIdx.x;
  const int w = t >> 6, lane = t & 63;
  const int q = lane >> 4, c = lane & 15;
  const int wj = w >> 1, wcol = w & 1;    // GEMM1: 4x2 wave grid (32j x 64i each)
  const int wd = w >> 1, wi = w & 1;      // GEMM2: 4x2 wave grid (64d x 64i each)
  const int i0 = blockIdx.x * BI;
  const int chunk0 = blockIdx.y * CHUNK;
  const bool gen = (chunk0 < Bn);
  const int swz = (c & 7) * 8;            // per-lane constant XOR
  const int jsteps = Ttot >> 5;

  // ---- stage resident G tile (128 rows x 256 k, swizzled); 512 thr -> 2 row-halves ----
  const int srow = t >> 3;                               // 0..63
  const int scol = ((t & 7) * 8) ^ ((srow & 7) * 8);     // source col within 64
  {
    const ushort_t* g0 = Tb + (size_t)(i0 + srow) * D_DIM;
    const ushort_t* g1 = Tb + (size_t)(i0 + 64 + srow) * D_DIM;
    #pragma unroll
    for (int kq = 0; kq < 4; kq++) {
      g2l16(g0 + kq * 64 + scol, Gsm + kq * 8192 + t * 8);
      g2l16(g1 + kq * 64 + scol, Gsm + kq * 8192 + 4096 + t * 8);
    }
  }

  f32x4 accO[4][4];
  #pragma unroll
  for (int m = 0; m < 4; m++)
    #pragma unroll
    for (int n = 0; n < 4; n++) accO[m][n] = (f32x4)0.f;
  float rs[4] = {0.f, 0.f, 0.f, 0.f};
  float ni[4];
  #pragma unroll
  for (int nt = 0; nt < 4; nt++) ni[nt] = nrm[i0 + wcol * 64 + nt * 16 + c];

  // persistent GEMM1 af prefetch (ks=0 of current tile)
  bf16x8 af0c, af1c;
  {
    const ushort_t* ap = TbF + ((size_t)((chunk0 >> 4) + wj * 2) * 8) * 512 + lane * 8;
    af0c = *(const bf16x8*)ap;
    af1c = *(const bf16x8*)(ap + 4096);
  }

  __syncthreads();   // Gsm ready

  for (int jt = 0; jt < CHUNK; jt += TJ) {
    const int j0g = chunk0 + jt;
    ushort_t* Kbuf = Ksm[(jt >> 7) & 1];
    const ushort_t* afp = TbF + ((size_t)((j0g >> 4) + wj * 2) * 8) * 512 + lane * 8;
    const bool dt = gen && (j0g == i0);   // diagonal tile (hoisted)

    // prefetch nrm[j] for this tile's epilogue (hidden under GEMM1)
    float4 njv[2];
    #pragma unroll
    for (int mt = 0; mt < 2; mt++)
      njv[mt] = *(const float4*)&nrm[j0g + wj * 32 + mt * 16 + q * 4];

    // ---- GEMM1: S^T[32j x 64i] per wave, K=256; af global (dbuf), bf from Gsm ----
    f32x4 acc1[2][4];
    #pragma unroll
    for (int m = 0; m < 2; m++)
      #pragma unroll
      for (int n = 0; n < 4; n++) acc1[m][n] = (f32x4)0.f;

    #pragma unroll
    for (int ks = 0; ks < 8; ks++) {
      bf16x8 afn0, afn1;
      if (ks < 7) {
        afn0 = *(const bf16x8*)(afp + (ks + 1) * 512);
        afn1 = *(const bf16x8*)(afp + 4096 + (ks + 1) * 512);
      }
      bf16x8 bf[4];
      #pragma unroll
      for (int nt = 0; nt < 4; nt++)
        bf[nt] = *(const bf16x8*)&Gsm[(ks >> 1) * 8192 + (wcol * 64 + nt * 16 + c) * 64 + ((((ks & 1) * 32) + q * 8) ^ swz)];
      #pragma unroll
      for (int nt = 0; nt < 4; nt++) {
        acc1[0][nt] = __builtin_amdgcn_mfma_f32_16x16x32_bf16(af0c, bf[nt], acc1[0][nt], 0, 0, 0);
        acc1[1][nt] = __builtin_amdgcn_mfma_f32_16x16x32_bf16(af1c, bf[nt], acc1[1][nt], 0, 0, 0);
      }
      if (ks < 7) { af0c = afn0; af1c = afn1; }
    }

    // ---- epilogue: kv = exp(-dist/20), rowsums, pack -> Kbuf ----
    #pragma unroll
    for (int mt = 0; mt < 2; mt++) {
      const int jl = wj * 32 + mt * 16 + q * 4;   // local j of reg 0
      const int jb = j0g + jl;                    // global j
      const float nj[4] = {njv[mt].x, njv[mt].y, njv[mt].z, njv[mt].w};
      #pragma unroll
      for (int nt = 0; nt < 4; nt++) {
        const int il = wcol * 64 + nt * 16 + c;
        const int ig = i0 + il;
        uint32_t pb[4];
        #pragma unroll
        for (int reg = 0; reg < 4; reg++) {
          float sq = fmaxf(ni[nt] + nj[reg] - 2.f * acc1[mt][nt][reg], 0.f);
          float dd = fast_sqrt(sq);
          float kv = fast_exp2(dd * -0.07213475204444817f);  // exp(-dd/20)
          if (dt && (jb + reg == ig)) kv = 0.f;
          rs[nt] += kv;
          union { float f; uint32_t u; } uu; uu.f = kv; pb[reg] = uu.u;
        }
        uint2 pk;  // truncating bf16 pack
        pk.x = __builtin_amdgcn_perm(pb[1], pb[0], 0x07060302u);
        pk.y = __builtin_amdgcn_perm(pb[3], pb[2], 0x07060302u);
        *(uint2*)&Kbuf[il * 128 + (jl ^ swz)] = pk;
      }
    }
    __syncthreads();   // Kbuf ready (sole barrier; dbuf covers cross-tile reuse)

    // ---- GEMM2: O^T[64d x 64i] per wave, K=128; a2 global (dbuf), kf Ksm (dbuf) ----
    const ushort_t* a2p = TTF + ((size_t)(wd * 4) * jsteps + (j0g >> 5)) * 512 + lane * 8;
    const size_t mstride = (size_t)jsteps * 512;
    bf16x8 a2c[4], kfc[4];
    #pragma unroll
    for (int mt = 0; mt < 4; mt++)
      a2c[mt] = *(const bf16x8*)(a2p + mt * mstride);
    #pragma unroll
    for (int nt = 0; nt < 4; nt++)
      kfc[nt] = *(const bf16x8*)&Kbuf[(wi * 64 + nt * 16 + c) * 128 + ((q * 8) ^ swz)];

    // issue next tile's GEMM1 ks=0 af prefetch (in flight through GEMM2)
    {
      const int jn = (jt + TJ < CHUNK) ? (j0g + TJ) : chunk0;
      const ushort_t* ap = TbF + ((size_t)((jn >> 4) + wj * 2) * 8) * 512 + lane * 8;
      af0c = *(const bf16x8*)ap;
      af1c = *(const bf16x8*)(ap + 4096);
    }

    #pragma unroll
    for (int ks = 0; ks < 4; ks++) {
      bf16x8 a2n[4], kfn[4];
      if (ks < 3) {
        #pragma unroll
        for (int mt = 0; mt < 4; mt++)
          a2n[mt] = *(const bf16x8*)(a2p + mt * mstride + (ks + 1) * 512);
        #pragma unroll
        for (int nt = 0; nt < 4; nt++)
          kfn[nt] = *(const bf16x8*)&Kbuf[(wi * 64 + nt * 16 + c) * 128 + ((((ks + 1) * 32) + q * 8) ^ swz)];
      }
      #pragma unroll
      for (int mt = 0; mt < 4; mt++)
        #pragma unroll
        for (int nt = 0; nt < 4; nt++)
          accO[mt][nt] = __builtin_amdgcn_mfma_f32_16x16x32_bf16(a2c[mt], kfc[nt], accO[mt][nt], 0, 0, 0);
      if (ks < 3) {
        #pragma unroll
        for (int mt = 0; mt < 4; mt++) a2c[mt] = a2n[mt];
        #pragma unroll
        for (int nt = 0; nt < 4; nt++) kfc[nt] = kfn[nt];
      }
    }
    // no barrier: next tile writes the other Ksm buffer
  }

  // rowsum partials -> sg/sp
  float* S = gen ? sg : sp;
  #pragma unroll
  for (int nt = 0; nt < 4; nt++) {
    float r = rs[nt];
    r += __shfl_xor(r, 16, 64);
    r += __shfl_xor(r, 32, 64);
    if (lane < 16) atomicAdd(&S[i0 + wcol * 64 + nt * 16 + lane], r);
  }
  // O^T partials -> Part[chunk][i][d] (f32x4, 16B aligned)
  float* Pdst = Part + (size_t)blockIdx.y * ((size_t)8192 * D_DIM);
  #pragma unroll
  for (int mt = 0; mt < 4; mt++)
    #pragma unroll
    for (int nt = 0; nt < 4; nt++) {
      const int d = wd * 64 + mt * 16 + q * 4;
      const int ig = i0 + wi * 64 + nt * 16 + c;
      *(f32x4*)&Pdst[(size_t)ig * D_DIM + d] = accO[mt][nt];
    }
}

// ---------------- combine: out = sg*sum(pos parts) - sp*sum(gen parts) ----------------
__global__ __launch_bounds__(256) void
combine_kernel(float* __restrict__ out, const float* __restrict__ Part,
               const float* __restrict__ sg, const float* __restrict__ sp)
{
  const size_t idx = (size_t)blockIdx.x * 256 + threadIdx.x;   // f32x4 index
  const size_t qstride = (size_t)8192 * (D_DIM / 4);
  const int i = (int)(idx >> 6);
  const f32x4* p = (const f32x4*)Part;
  f32x4 g0 = p[idx], g1 = p[idx + qstride];
  f32x4 p0 = p[idx + 2 * qstride], p1 = p[idx + 3 * qstride];
  const float sgv = sg[i], spv = sp[i];
  f32x4 r;
  #pragma unroll
  for (int k = 0; k < 4; k++) r[k] = sgv * (p0[k] + p1[k]) - spv * (g0[k] + g1[k]);
  ((f32x4*)out)[idx] = r;
}

extern "C" void kernel_launch(void* const* d_in, const int* in_sizes, int n_in,
                              void* d_out, int out_size, void* d_ws, size_t ws_size,
                              hipStream_t stream)
{
  const float* G = (const float*)d_in[0];
  const float* P = (const float*)d_in[1];
  const int Bn = in_sizes[0] / D_DIM;   // 8192
  const int Xn = in_sizes[1] / D_DIM;   // 8192
  const int Ttot = Bn + Xn;             // 16384

  // workspace (~56.4 MiB)
  uint8_t* ws = (uint8_t*)d_ws;
  size_t off = 0;
  ushort_t* Tb  = (ushort_t*)(ws + off); off += (size_t)Ttot * D_DIM * 2;  // 8 MiB
  ushort_t* TbF = (ushort_t*)(ws + off); off += (size_t)Ttot * D_DIM * 2;  // 8 MiB
  ushort_t* TTF = (ushort_t*)(ws + off); off += (size_t)Ttot * D_DIM * 2;  // 8 MiB
  float* nrm = (float*)(ws + off); off += (size_t)Ttot * 4;
  float* sg  = (float*)(ws + off); off += (size_t)Bn * 4;
  float* sp  = (float*)(ws + off); off += (size_t)Bn * 4;
  off = (off + 255) & ~(size_t)255;
  float* Part = (float*)(ws + off); off += (size_t)4 * Bn * D_DIM * 4;     // 32 MiB
  if (ws_size < off) return;  // clean-fail signature if ws too small

  // zero nrm + sg + sp (contiguous)
  hipMemsetAsync(nrm, 0, ((size_t)Ttot + 2 * (size_t)Bn) * sizeof(float), stream);

  prep_ABT<<<Ttot / 32, 256, 0, stream>>>(G, P, Tb, TbF, TTF, nrm, Bn, Ttot);
  fused_kernel<<<dim3(Bn / BI, Ttot / CHUNK), 512, 0, stream>>>(
      Tb, TbF, TTF, nrm, sg, sp, Part, Bn, Ttot);
  combine_kernel<<<(Bn * D_DIM / 4) / 256, 256, 0, stream>>>((float*)d_out, Part, sg, sp);
}